// Round 1
// baseline (477.771 us; speedup 1.0000x reference)
//
#include <hip/hip_runtime.h>
#include <hip/hip_bf16.h>

// AttentionAggregator: fused one-pass kernel.
// Per batch b (262144 total): attention scores over N=4 members of D=256,
// softmax weights, tiny MLP classifier (4->128->64->2 with eval-BN), then
// conditional pooling (argmax-gather if cls==1 else weighted sum).
// One wave per batch; x is loaded once into registers and reused for dots,
// pooling and gather. w2 (64x128) lives in per-lane registers (row j in lane j).

namespace {
constexpr int kBatch = 262144;
constexpr float kEps = 1e-5f;
}

__device__ __forceinline__ float lane_bcast(float v, int srclane) {
    return __uint_as_float(__builtin_amdgcn_readlane(__float_as_uint(v), srclane));
}

__device__ __forceinline__ float wave_sum(float v) {
#pragma unroll
    for (int d = 1; d < 64; d <<= 1) v += __shfl_xor(v, d, 64);
    return v;
}

__device__ __forceinline__ float dot4(float4 a, float4 b) {
    return fmaf(a.w, b.w, fmaf(a.z, b.z, fmaf(a.y, b.y, a.x * b.x)));
}

__global__ __launch_bounds__(256, 2) void agg_fused(
    const float* __restrict__ x, const float* __restrict__ mask,
    const float* __restrict__ attn_w, const float* __restrict__ attn_b,
    const float* __restrict__ w1, const float* __restrict__ b1,
    const float* __restrict__ g1, const float* __restrict__ be1,
    const float* __restrict__ m1, const float* __restrict__ v1,
    const float* __restrict__ w2, const float* __restrict__ b2,
    const float* __restrict__ g2, const float* __restrict__ be2,
    const float* __restrict__ m2, const float* __restrict__ v2,
    const float* __restrict__ w3, const float* __restrict__ b3,
    float* __restrict__ out_ret, float* __restrict__ out_w,
    float* __restrict__ out_cls, int bpw)
{
    const int lane = threadIdx.x & 63;
    const int wid  = blockIdx.x * (blockDim.x >> 6) + (threadIdx.x >> 6);

    // ---- loop-invariant per-lane parameters (registers) ----
    const float4 aw  = *reinterpret_cast<const float4*>(attn_w + lane * 4);
    const float  ab  = attn_b[0];
    const float4 w1a = *reinterpret_cast<const float4*>(w1 + lane * 4);         // row lane
    const float4 w1b = *reinterpret_cast<const float4*>(w1 + (lane + 64) * 4);  // row lane+64
    const float  b1a = b1[lane],   b1b = b1[lane + 64];
    const float  g1a = g1[lane],   g1b = g1[lane + 64];
    const float  be1a = be1[lane], be1b = be1[lane + 64];
    const float  m1a = m1[lane],   m1b = m1[lane + 64];
    const float  d1a = sqrtf(v1[lane] + kEps), d1b = sqrtf(v1[lane + 64] + kEps);
    const float  b2j = b2[lane], g2j = g2[lane], be2j = be2[lane], m2j = m2[lane];
    const float  d2j = sqrtf(v2[lane] + kEps);
    const float  w30 = w3[lane], w31 = w3[64 + lane];
    const float  b30 = b3[0], b31 = b3[1];

    // w2 row `lane` resident in registers: 32 float4 = 128 VGPRs, loop-invariant.
    float4 w2r[32];
#pragma unroll
    for (int c = 0; c < 32; ++c)
        w2r[c] = *reinterpret_cast<const float4*>(w2 + lane * 128 + c * 4);

    const int b0 = wid * bpw;
    for (int i = 0; i < bpw; ++i) {
        const int b = b0 + i;
        const float* xb = x + (size_t)b * 1024;

        // ---- load x[b] once: lane owns d in [4*lane, 4*lane+4) for all 4 rows ----
        const float4 xv0 = *reinterpret_cast<const float4*>(xb + 0 * 256 + lane * 4);
        const float4 xv1 = *reinterpret_cast<const float4*>(xb + 1 * 256 + lane * 4);
        const float4 xv2 = *reinterpret_cast<const float4*>(xb + 2 * 256 + lane * 4);
        const float4 xv3 = *reinterpret_cast<const float4*>(xb + 3 * 256 + lane * 4);

        // ---- attention scores: tanh(x . attn_w + attn_b) ----
        float s0 = wave_sum(dot4(xv0, aw));
        float s1 = wave_sum(dot4(xv1, aw));
        float s2 = wave_sum(dot4(xv2, aw));
        float s3 = wave_sum(dot4(xv3, aw));
        float a0 = tanhf(s0 + ab);
        float a1 = tanhf(s1 + ab);
        float a2 = tanhf(s2 + ab);
        float a3 = tanhf(s3 + ab);

        // + mask, softmax over the 4 members (subtract max, exp, normalize)
        const float4 mk = *reinterpret_cast<const float4*>(mask + (size_t)b * 4);
        a0 += mk.x; a1 += mk.y; a2 += mk.z; a3 += mk.w;
        const float amax = fmaxf(fmaxf(a0, a1), fmaxf(a2, a3));
        const float e0 = expf(a0 - amax), e1 = expf(a1 - amax);
        const float e2 = expf(a2 - amax), e3 = expf(a3 - amax);
        const float esum = ((e0 + e1) + e2) + e3;
        const float wt0 = e0 / esum, wt1 = e1 / esum, wt2 = e2 / esum, wt3 = e3 / esum;

        // ---- layer 1: h1 = BN(ReLU(wf @ w1.T + b1)); lane owns rows lane, lane+64 ----
        float pre = fmaf(wt3, w1a.w, fmaf(wt2, w1a.z, fmaf(wt1, w1a.y, wt0 * w1a.x))) + b1a;
        float r   = fmaxf(pre, 0.0f);
        const float h1A = (g1a * (r - m1a)) / d1a + be1a;
        pre = fmaf(wt3, w1b.w, fmaf(wt2, w1b.z, fmaf(wt1, w1b.y, wt0 * w1b.x))) + b1b;
        r   = fmaxf(pre, 0.0f);
        const float h1B = (g1b * (r - m1b)) / d1b + be1b;

        // ---- layer 2: h2[lane] = BN(ReLU(h1 . w2[lane,:] + b2)) ----
        // h1 is distributed (h1A=h1[lane], h1B=h1[lane+64]); broadcast via v_readlane.
        float acc0 = 0.0f, acc1 = 0.0f, acc2 = 0.0f, acc3 = 0.0f;
#pragma unroll
        for (int c = 0; c < 16; ++c) {
            const float4 wv = w2r[c];
            acc0 = fmaf(lane_bcast(h1A, 4 * c + 0), wv.x, acc0);
            acc1 = fmaf(lane_bcast(h1A, 4 * c + 1), wv.y, acc1);
            acc2 = fmaf(lane_bcast(h1A, 4 * c + 2), wv.z, acc2);
            acc3 = fmaf(lane_bcast(h1A, 4 * c + 3), wv.w, acc3);
        }
#pragma unroll
        for (int c = 0; c < 16; ++c) {
            const float4 wv = w2r[16 + c];
            acc0 = fmaf(lane_bcast(h1B, 4 * c + 0), wv.x, acc0);
            acc1 = fmaf(lane_bcast(h1B, 4 * c + 1), wv.y, acc1);
            acc2 = fmaf(lane_bcast(h1B, 4 * c + 2), wv.z, acc2);
            acc3 = fmaf(lane_bcast(h1B, 4 * c + 3), wv.w, acc3);
        }
        float h2p = ((acc0 + acc1) + (acc2 + acc3)) + b2j;
        h2p = fmaxf(h2p, 0.0f);
        const float h2v = (g2j * (h2p - m2j)) / d2j + be2j;

        // ---- output head: logits -> softmax -> biased argmax ----
        const float z0 = wave_sum(h2v * w30) + b30;
        const float z1 = wave_sum(h2v * w31) + b31;
        const float zm = fmaxf(z0, z1);
        const float q0 = expf(z0 - zm), q1 = expf(z1 - zm);
        const float qs = q0 + q1;
        const float p0 = q0 / qs;
        const float p1 = q1 / qs - 0.5f;
        const int cls = (p1 > p0) ? 1 : 0;   // argmax keeps first index on ties

        // ---- argmax over attention weights (first occurrence of max) ----
        int midx = 0; float mval = wt0;
        if (wt1 > mval) { mval = wt1; midx = 1; }
        if (wt2 > mval) { mval = wt2; midx = 2; }
        if (wt3 > mval) { mval = wt3; midx = 3; }

        // gathered = x[b, midx, :]
        const float4 g01 = (midx == 1) ? xv1 : xv0;
        const float4 g23 = (midx == 3) ? xv3 : xv2;
        const float4 gth = (midx >= 2) ? g23 : g01;

        // pooled = sum_n w_n * x[b,n,:]  (sequential n order like the reference)
        float4 pl;
        pl.x = fmaf(wt3, xv3.x, fmaf(wt2, xv2.x, fmaf(wt1, xv1.x, wt0 * xv0.x)));
        pl.y = fmaf(wt3, xv3.y, fmaf(wt2, xv2.y, fmaf(wt1, xv1.y, wt0 * xv0.y)));
        pl.z = fmaf(wt3, xv3.z, fmaf(wt2, xv2.z, fmaf(wt1, xv1.z, wt0 * xv0.z)));
        pl.w = fmaf(wt3, xv3.w, fmaf(wt2, xv2.w, fmaf(wt1, xv1.w, wt0 * xv0.w)));

        const float4 ret = (cls == 1) ? gth : pl;
        *reinterpret_cast<float4*>(out_ret + (size_t)b * 256 + lane * 4) = ret;

        if (lane == 0) {
            *reinterpret_cast<float4*>(out_w + (size_t)b * 4) =
                make_float4(wt0, wt1, wt2, wt3);
            out_cls[b] = (float)cls;
        }
    }
}

extern "C" void kernel_launch(void* const* d_in, const int* in_sizes, int n_in,
                              void* d_out, int out_size, void* d_ws, size_t ws_size,
                              hipStream_t stream) {
    const float* x      = (const float*)d_in[0];
    const float* mask   = (const float*)d_in[1];
    const float* attn_w = (const float*)d_in[2];
    const float* attn_b = (const float*)d_in[3];
    const float* w1     = (const float*)d_in[4];
    const float* b1     = (const float*)d_in[5];
    const float* g1     = (const float*)d_in[6];
    const float* be1    = (const float*)d_in[7];
    const float* m1     = (const float*)d_in[8];
    const float* v1     = (const float*)d_in[9];
    const float* w2     = (const float*)d_in[10];
    const float* b2     = (const float*)d_in[11];
    const float* g2     = (const float*)d_in[12];
    const float* be2    = (const float*)d_in[13];
    const float* m2     = (const float*)d_in[14];
    const float* v2     = (const float*)d_in[15];
    const float* w3     = (const float*)d_in[16];
    const float* b3     = (const float*)d_in[17];

    float* out = (float*)d_out;
    float* out_ret = out;                                  // [B, 256]
    float* out_w   = out + (size_t)262144 * 256;           // [B, 4, 1]
    float* out_cls = out_w + (size_t)262144 * 4;           // [B]

    const int threads = 256;
    const int blocks  = 4096;                 // 16384 waves -> 16 batches per wave
    const int waves   = blocks * (threads / 64);
    const int bpw     = 262144 / waves;

    agg_fused<<<blocks, threads, 0, stream>>>(
        x, mask, attn_w, attn_b, w1, b1, g1, be1, m1, v1,
        w2, b2, g2, be2, m2, v2, w3, b3,
        out_ret, out_w, out_cls, bpw);
}

// Round 2
// 337.833 us; speedup vs baseline: 1.4142x; 1.4142x over previous
//
#include <hip/hip_runtime.h>
#include <hip/hip_bf16.h>

// AttentionAggregator: fused one-pass kernel, round 2.
// Changes vs R1: (1) wave reductions via DPP (VALU pipe, ~40cyc chain) instead
// of __shfl_xor/ds_bpermute (~700cyc chain); (2) software prefetch of next
// batch's x (double-buffered registers); (3) one softmax division + inv-std
// BN; (4) classifier head reduced to a single reduction: cls = [z1-z0 > ln3].

namespace {
constexpr float kEps = 1e-5f;
constexpr float kLn3 = 1.0986122886681098f;  // ln(3)
}

__device__ __forceinline__ float lane_bcast(float v, int srclane) {
    return __uint_as_float(__builtin_amdgcn_readlane(__float_as_uint(v), srclane));
}

template <int CTRL>
__device__ __forceinline__ float dpp_add(float x) {
    // x + dpp_shift(x); bound_ctrl=true -> out-of-range lanes contribute 0.
    int s = __builtin_amdgcn_update_dpp(0, __float_as_int(x), CTRL, 0xF, 0xF, true);
    return x + __int_as_float(s);
}

// Full 64-lane sum on the VALU pipe; total lands in lane 63.
__device__ __forceinline__ float dpp_sum63(float x) {
    x = dpp_add<0x111>(x);  // row_shr:1
    x = dpp_add<0x112>(x);  // row_shr:2
    x = dpp_add<0x114>(x);  // row_shr:4
    x = dpp_add<0x118>(x);  // row_shr:8
    x = dpp_add<0x142>(x);  // row_bcast:15
    x = dpp_add<0x143>(x);  // row_bcast:31
    return x;
}

__device__ __forceinline__ float dot4(float4 a, float4 b) {
    return fmaf(a.w, b.w, fmaf(a.z, b.z, fmaf(a.y, b.y, a.x * b.x)));
}

__global__ __launch_bounds__(256, 2) void agg_fused(
    const float* __restrict__ x, const float* __restrict__ mask,
    const float* __restrict__ attn_w, const float* __restrict__ attn_b,
    const float* __restrict__ w1, const float* __restrict__ b1,
    const float* __restrict__ g1, const float* __restrict__ be1,
    const float* __restrict__ m1, const float* __restrict__ v1,
    const float* __restrict__ w2, const float* __restrict__ b2,
    const float* __restrict__ g2, const float* __restrict__ be2,
    const float* __restrict__ m2, const float* __restrict__ v2,
    const float* __restrict__ w3, const float* __restrict__ b3,
    float* __restrict__ out_ret, float* __restrict__ out_w,
    float* __restrict__ out_cls, int bpw)
{
    const int lane = threadIdx.x & 63;
    const int wid  = blockIdx.x * (blockDim.x >> 6) + (threadIdx.x >> 6);

    // ---- loop-invariant per-lane parameters ----
    const float4 aw  = *reinterpret_cast<const float4*>(attn_w + lane * 4);
    const float  ab  = attn_b[0];
    const float4 w1a = *reinterpret_cast<const float4*>(w1 + lane * 4);
    const float4 w1b = *reinterpret_cast<const float4*>(w1 + (lane + 64) * 4);
    const float  b1a = b1[lane],   b1b = b1[lane + 64];
    const float  g1a = g1[lane],   g1b = g1[lane + 64];
    const float  be1a = be1[lane], be1b = be1[lane + 64];
    const float  m1a = m1[lane],   m1b = m1[lane + 64];
    const float  rd1a = 1.0f / sqrtf(v1[lane] + kEps);
    const float  rd1b = 1.0f / sqrtf(v1[lane + 64] + kEps);
    const float  b2j = b2[lane], g2j = g2[lane], be2j = be2[lane], m2j = m2[lane];
    const float  rd2j = 1.0f / sqrtf(v2[lane] + kEps);
    const float  wd  = w3[64 + lane] - w3[lane];       // w3[1,:] - w3[0,:]
    const float  thr = kLn3 - (b3[1] - b3[0]);         // cls=1 iff sum(h2*wd) > thr

    // w2 row `lane` in registers (32 float4 = 128 VGPRs, loop-invariant).
    float4 w2r[32];
#pragma unroll
    for (int c = 0; c < 32; ++c)
        w2r[c] = *reinterpret_cast<const float4*>(w2 + lane * 128 + c * 4);

    const int b0 = wid * bpw;
    const float* xp = x    + (size_t)b0 * 1024 + lane * 4;
    const float* mp = mask + (size_t)b0 * 4;
    float*       rp = out_ret + (size_t)b0 * 256 + lane * 4;
    float*       wp = out_w   + (size_t)b0 * 4;
    float*       cp = out_cls + b0;

    auto body = [&](float4 xv0, float4 xv1, float4 xv2, float4 xv3,
                    float4 mk, int i) {
        // attention scores: tanh(x . attn_w + attn_b) + mask
        float r0 = dpp_sum63(dot4(xv0, aw));
        float r1 = dpp_sum63(dot4(xv1, aw));
        float r2 = dpp_sum63(dot4(xv2, aw));
        float r3 = dpp_sum63(dot4(xv3, aw));
        const float a0 = tanhf(lane_bcast(r0, 63) + ab) + mk.x;
        const float a1 = tanhf(lane_bcast(r1, 63) + ab) + mk.y;
        const float a2 = tanhf(lane_bcast(r2, 63) + ab) + mk.z;
        const float a3 = tanhf(lane_bcast(r3, 63) + ab) + mk.w;

        // softmax over 4 members
        const float amax = fmaxf(fmaxf(a0, a1), fmaxf(a2, a3));
        const float e0 = __expf(a0 - amax), e1 = __expf(a1 - amax);
        const float e2 = __expf(a2 - amax), e3 = __expf(a3 - amax);
        const float esum = ((e0 + e1) + e2) + e3;
        const float rs = 1.0f / esum;
        const float wt0 = e0 * rs, wt1 = e1 * rs, wt2 = e2 * rs, wt3 = e3 * rs;

        // layer 1 (rows lane, lane+64): BN(ReLU(wf @ w1.T + b1))
        float pre = fmaf(wt3, w1a.w, fmaf(wt2, w1a.z, fmaf(wt1, w1a.y, wt0 * w1a.x))) + b1a;
        float rr  = fmaxf(pre, 0.0f);
        const float h1A = g1a * (rr - m1a) * rd1a + be1a;
        pre = fmaf(wt3, w1b.w, fmaf(wt2, w1b.z, fmaf(wt1, w1b.y, wt0 * w1b.x))) + b1b;
        rr  = fmaxf(pre, 0.0f);
        const float h1B = g1b * (rr - m1b) * rd1b + be1b;

        // layer 2: h2[lane] = BN(ReLU(h1 . w2[lane,:] + b2)); h1 via readlane
        float acc0 = 0.0f, acc1 = 0.0f, acc2 = 0.0f, acc3 = 0.0f;
#pragma unroll
        for (int c = 0; c < 16; ++c) {
            const float4 wv = w2r[c];
            acc0 = fmaf(lane_bcast(h1A, 4 * c + 0), wv.x, acc0);
            acc1 = fmaf(lane_bcast(h1A, 4 * c + 1), wv.y, acc1);
            acc2 = fmaf(lane_bcast(h1A, 4 * c + 2), wv.z, acc2);
            acc3 = fmaf(lane_bcast(h1A, 4 * c + 3), wv.w, acc3);
        }
#pragma unroll
        for (int c = 0; c < 16; ++c) {
            const float4 wv = w2r[16 + c];
            acc0 = fmaf(lane_bcast(h1B, 4 * c + 0), wv.x, acc0);
            acc1 = fmaf(lane_bcast(h1B, 4 * c + 1), wv.y, acc1);
            acc2 = fmaf(lane_bcast(h1B, 4 * c + 2), wv.z, acc2);
            acc3 = fmaf(lane_bcast(h1B, 4 * c + 3), wv.w, acc3);
        }
        float h2p = ((acc0 + acc1) + (acc2 + acc3)) + b2j;
        h2p = fmaxf(h2p, 0.0f);
        const float h2v = g2j * (h2p - m2j) * rd2j + be2j;

        // head: cls = 1 iff z1 - z0 > ln3  (<=> p1 - 0.5 > p0)
        float dz = dpp_sum63(h2v * wd);
        const float dzs = lane_bcast(dz, 63);
        const int cls = (dzs > thr) ? 1 : 0;

        // argmax over attention weights (first occurrence)
        int midx = 0; float mval = wt0;
        if (wt1 > mval) { mval = wt1; midx = 1; }
        if (wt2 > mval) { mval = wt2; midx = 2; }
        if (wt3 > mval) { mval = wt3; midx = 3; }

        const float4 g01 = (midx == 1) ? xv1 : xv0;
        const float4 g23 = (midx == 3) ? xv3 : xv2;
        const float4 gth = (midx >= 2) ? g23 : g01;

        float4 pl;
        pl.x = fmaf(wt3, xv3.x, fmaf(wt2, xv2.x, fmaf(wt1, xv1.x, wt0 * xv0.x)));
        pl.y = fmaf(wt3, xv3.y, fmaf(wt2, xv2.y, fmaf(wt1, xv1.y, wt0 * xv0.y)));
        pl.z = fmaf(wt3, xv3.z, fmaf(wt2, xv2.z, fmaf(wt1, xv1.z, wt0 * xv0.z)));
        pl.w = fmaf(wt3, xv3.w, fmaf(wt2, xv2.w, fmaf(wt1, xv1.w, wt0 * xv0.w)));

        const float4 ret = (cls == 1) ? gth : pl;
        *reinterpret_cast<float4*>(rp + (size_t)i * 256) = ret;
        if (lane == 0) {
            *reinterpret_cast<float4*>(wp + (size_t)i * 4) =
                make_float4(wt0, wt1, wt2, wt3);
            cp[i] = (float)cls;
        }
    };

    // prologue: load batch 0 into buffer A
    float4 ax0 = *reinterpret_cast<const float4*>(xp + 0);
    float4 ax1 = *reinterpret_cast<const float4*>(xp + 256);
    float4 ax2 = *reinterpret_cast<const float4*>(xp + 512);
    float4 ax3 = *reinterpret_cast<const float4*>(xp + 768);
    float4 amk = *reinterpret_cast<const float4*>(mp);

    for (int i = 0; i < bpw; i += 2) {
        // prefetch batch i+1 into buffer B (always valid: bpw is even)
        const float* xq = xp + 1024;
        float4 bx0 = *reinterpret_cast<const float4*>(xq + 0);
        float4 bx1 = *reinterpret_cast<const float4*>(xq + 256);
        float4 bx2 = *reinterpret_cast<const float4*>(xq + 512);
        float4 bx3 = *reinterpret_cast<const float4*>(xq + 768);
        float4 bmk = *reinterpret_cast<const float4*>(mp + 4);

        body(ax0, ax1, ax2, ax3, amk, i);

        // prefetch batch i+2 into buffer A (clamped on the last iteration)
        const float* xr = (i + 2 < bpw) ? (xp + 2048) : xp;
        const float* mr = (i + 2 < bpw) ? (mp + 8) : mp;
        ax0 = *reinterpret_cast<const float4*>(xr + 0);
        ax1 = *reinterpret_cast<const float4*>(xr + 256);
        ax2 = *reinterpret_cast<const float4*>(xr + 512);
        ax3 = *reinterpret_cast<const float4*>(xr + 768);
        amk = *reinterpret_cast<const float4*>(mr);

        body(bx0, bx1, bx2, bx3, bmk, i + 1);

        xp += 2048;
        mp += 8;
    }
}

extern "C" void kernel_launch(void* const* d_in, const int* in_sizes, int n_in,
                              void* d_out, int out_size, void* d_ws, size_t ws_size,
                              hipStream_t stream) {
    const float* x      = (const float*)d_in[0];
    const float* mask   = (const float*)d_in[1];
    const float* attn_w = (const float*)d_in[2];
    const float* attn_b = (const float*)d_in[3];
    const float* w1     = (const float*)d_in[4];
    const float* b1     = (const float*)d_in[5];
    const float* g1     = (const float*)d_in[6];
    const float* be1    = (const float*)d_in[7];
    const float* m1     = (const float*)d_in[8];
    const float* v1     = (const float*)d_in[9];
    const float* w2     = (const float*)d_in[10];
    const float* b2     = (const float*)d_in[11];
    const float* g2     = (const float*)d_in[12];
    const float* be2    = (const float*)d_in[13];
    const float* m2     = (const float*)d_in[14];
    const float* v2     = (const float*)d_in[15];
    const float* w3     = (const float*)d_in[16];
    const float* b3     = (const float*)d_in[17];

    float* out = (float*)d_out;
    float* out_ret = out;                         // [B, 256]
    float* out_w   = out + (size_t)262144 * 256;  // [B, 4, 1]
    float* out_cls = out_w + (size_t)262144 * 4;  // [B]

    const int threads = 256;
    const int blocks  = 4096;                     // 16384 waves -> 16 batches/wave
    const int waves   = blocks * (threads / 64);
    const int bpw     = 262144 / waves;

    agg_fused<<<blocks, threads, 0, stream>>>(
        x, mask, attn_w, attn_b, w1, b1, g1, be1, m1, v1,
        w2, b2, g2, be2, m2, v2, w3, b3,
        out_ret, out_w, out_cls, bpw);
}